// Round 7
// baseline (1278.027 us; speedup 1.0000x reference)
//
#include <hip/hip_runtime.h>
#include <math.h>

#define B_ 512
#define T_ 200
#define D_ 256
#define H_ 256

typedef unsigned int   u32;
typedef unsigned short u16;
typedef _Float16 half8 __attribute__((ext_vector_type(8)));
typedef float f32x4 __attribute__((ext_vector_type(4)));

__device__ __forceinline__ float sigmoid_f(float x) { return 1.0f / (1.0f + __expf(-x)); }
__device__ __forceinline__ float tanh_f(float x)    { return 1.0f - 2.0f / (__expf(2.0f * x) + 1.0f); }
__device__ __forceinline__ u16 f16b(float x) { union { _Float16 h; u16 u; } r; r.h = (_Float16)x; return r.u; }
__device__ __forceinline__ float f16f(u16 v) { union { u16 u; _Float16 h; } r; r.u = v; return (float)r.h; }

// Raw barrier: drain LDS ops only; global loads/stores stay in flight.
#define BARX() asm volatile("s_waitcnt lgkmcnt(0)\n\ts_barrier" ::: "memory")

// Fragment-major f16 weights: [tile][kstep][lane][8]; lane l holds
// W[k = kstep*32 + (l>>4)*8 + 0..7][col = tile*16 + (l&15)].
// g_Wt: x-part rows 0..255 (tiles 0..15 reset, 16..31 update, 32..47 cand).
// g_Wh: h-part rows 256..511 (same tiling).
__device__ __attribute__((aligned(16))) _Float16 g_Wt[48 * 8 * 64 * 8];
__device__ __attribute__((aligned(16))) _Float16 g_Wh[48 * 8 * 64 * 8];

__global__ __launch_bounds__(512) void prep_wt(
    const float* __restrict__ gk, const float* __restrict__ ck)
{
    const int  blk  = blockIdx.x;        // 0..95
    const bool isH  = blk >= 48;
    const int  ct   = isH ? blk - 48 : blk;
    const int  step = threadIdx.x >> 6;
    const int  lane = threadIdx.x & 63;
    const bool isG  = ct < 32;
    const float* W  = isG ? gk : ck;
    const int  nc   = isG ? 512 : 256;
    const int  col  = (isG ? ct : ct - 32) * 16 + (lane & 15);
    const int  k0   = step * 32 + (lane >> 4) * 8 + (isH ? 256 : 0);
    half8 v;
    #pragma unroll
    for (int j = 0; j < 8; ++j)
        v[j] = (_Float16)W[(size_t)(k0 + j) * nc + col];
    _Float16* dst = isH ? g_Wh : g_Wt;
    *(half8*)&dst[((size_t)(ct * 8 + step) * 64 + lane) * 8] = v;
}

// ============================================================================
// Projection GEMM -> packed permuted layouts (unchanged from R5/R6, verified):
//   pgI: [m][256] u32, entry e(c) = (c>>6)*64 + (c&15)*4 + ((c>>4)&3)
//        holds (reset_c | update_c<<16); pcI: [m][256] u16, same perm.
// ============================================================================
__global__ __launch_bounds__(512) __attribute__((amdgpu_waves_per_eu(2, 2)))
void proj_mfma(
    const float* __restrict__ x, const float* __restrict__ gb,
    const float* __restrict__ cb,
    u32* pgI,                     // aliases d_out: [102400][256] u32
    u16* __restrict__ pcI)        // ws: [102400][256] u16
{
    __shared__ __attribute__((aligned(16))) u32 smem[2][64][132];
    _Float16 (*xs)[264] = (_Float16(*)[264])&smem[0][0][0];

    const int tid  = threadIdx.x;
    const int m0   = blockIdx.x * 64;
    const int lane = tid & 63;
    const int w    = tid >> 6;
    const int qr4  = (lane >> 4) * 4;
    const int cl   = lane & 15;
    const int le   = (w >> 2) * 64 + cl * 4 + (w & 3);

    #pragma unroll
    for (int q = 0; q < 8; ++q) {
        int f = tid + 512 * q;
        int r = f >> 6, c = (f & 63) * 4;
        float4 v = *(const float4*)&x[(size_t)(m0 + r) * 256 + c];
        uint2 p;
        union { _Float16 h[2]; u32 u; } t0, t1;
        t0.h[0] = (_Float16)v.x; t0.h[1] = (_Float16)v.y;
        t1.h[0] = (_Float16)v.z; t1.h[1] = (_Float16)v.w;
        p.x = t0.u; p.y = t1.u;
        *(uint2*)&xs[r][c] = p;
    }
    BARX();

    half8 xf[4][8];
    #pragma unroll
    for (int jt = 0; jt < 4; ++jt)
        #pragma unroll
        for (int kc = 0; kc < 8; ++kc)
            xf[jt][kc] = *(const half8*)&xs[jt * 16 + cl][kc * 32 + (lane >> 4) * 8];
    BARX();   // xs dead; smem[0] may now be overwritten

    #pragma unroll 1
    for (int p = 0; p < 6; ++p) {
        const int it = w + 8 * p;
        const _Float16* bp = &g_Wt[(size_t)it * 4096];
        half8 bf[8];
        #pragma unroll
        for (int kc = 0; kc < 8; ++kc)
            bf[kc] = *(const half8*)&bp[(kc * 64 + lane) * 8];

        f32x4 acc[4] = {};
        #pragma unroll
        for (int kc = 0; kc < 8; ++kc)
            #pragma unroll
            for (int jt = 0; jt < 4; ++jt)
                acc[jt] = __builtin_amdgcn_mfma_f32_16x16x32_f16(
                              xf[jt][kc], bf[kc], acc[jt], 0, 0, 0);

        const int n    = it * 16 + cl;
        const float bias = (p < 4) ? gb[n] : cb[n - 512];
        const int buf  = p & 1;
        u16* s16 = (u16*)&smem[buf][0][0];

        if (p < 2) {            // reset -> low halves
            #pragma unroll
            for (int jt = 0; jt < 4; ++jt)
                #pragma unroll
                for (int r = 0; r < 4; ++r)
                    s16[(jt * 16 + qr4 + r) * 264 + le * 2] = f16b(acc[jt][r] + bias);
        } else if (p < 4) {     // update -> high halves
            #pragma unroll
            for (int jt = 0; jt < 4; ++jt)
                #pragma unroll
                for (int r = 0; r < 4; ++r)
                    s16[(jt * 16 + qr4 + r) * 264 + le * 2 + 1] = f16b(acc[jt][r] + bias);
            BARX();
            #pragma unroll
            for (int q = 0; q < 4; ++q) {
                int idx = tid + 512 * q;
                int row = idx >> 5, seg = idx & 31;
                uint4 v = *(const uint4*)&smem[buf][row][seg * 4];
                *(uint4*)&pgI[(size_t)(m0 + row) * 256 + 128 * buf + seg * 4] = v;
            }
        } else {                // cand -> u16 entries
            #pragma unroll
            for (int jt = 0; jt < 4; ++jt)
                #pragma unroll
                for (int r = 0; r < 4; ++r)
                    s16[(jt * 16 + qr4 + r) * 264 + le] = f16b(acc[jt][r] + bias);
            BARX();
            #pragma unroll
            for (int q = 0; q < 2; ++q) {
                int idx = tid + 512 * q;
                int row = idx >> 4, seg = idx & 15;
                uint4 v = *(const uint4*)((const u16*)&smem[buf][row][0] + seg * 8);
                *(uint4*)&pcI[(size_t)(m0 + row) * 256 + 128 * buf + seg * 8] = v;
            }
        }
        if (p == 2 || p == 3 || p == 4) BARX();
    }
}

// ============================================================================
// Recurrent kernel v7: ZERO persistent per-thread weight state.
// Evidence R2-R6: 192-reg weight arrays never stayed in arch VGPRs
// (VGPR_Count pinned at 128 under every hint); per-step scratch/AGPR
// reload was the hidden ~6000 cy/step. v7 is designed to FIT 128 regs:
//  - 1024 threads = 16 waves; wave w owns col-tile w of R, U, C (16 cols).
//  - Wr/Wu fragments streamed from g_Wh (L2-resident, all blocks share the
//    same 384 KB) each step: 8 dwordx4 per pass = 32 transient regs.
//  - Wc in LDS (128 KB, staged once); ha read once per k-step feeds both
//    R and U chains (1 half8 live).
//  - Peak live ~115 regs. 4 waves/SIMD for TLP. 2 lgkm-only barriers/step.
// 32 blocks x 16 batch rows; lane owns 4 rows x 1 col (D-layout verified).
// ============================================================================
__global__ __launch_bounds__(1024) void gru_rec7(
    const int* __restrict__ slen,
    const u32* pgI,                // aliases d_out: [m][256] u32 permuted
    const u16* __restrict__ pcI,   // ws: [m][256] u16 permuted
    float* out)                    // aliases pgI (row t stored after row t+1 read)
{
    __shared__ __attribute__((aligned(16))) _Float16 wc_lds[16 * 8 * 64 * 8]; // 128 KB
    __shared__ _Float16 h_lds[16][264];
    __shared__ _Float16 rh_lds[16][264];

    const int tid  = threadIdx.x;
    const int w    = tid >> 6;       // wave 0..15
    const int lane = tid & 63;
    const int qr   = lane >> 4;      // 0..3 (owns batch rows qr*4 + 0..3)
    const int cl   = lane & 15;      // column-within-tile
    const int b0   = blockIdx.x * 16;

    // ---- stage Wc (g_Wh tiles 32..47, 128 KB) into LDS ----
    {
        const uint4* srcv = (const uint4*)&g_Wh[32 * 8 * 64 * 8];
        uint4* dstv = (uint4*)wc_lds;
        for (int i = tid; i < 8192; i += 1024) dstv[i] = srcv[i];
    }
    // ---- init h = 0 ----
    for (int i = tid; i < 16 * 264; i += 1024)
        ((_Float16*)h_lds)[i] = (_Float16)0.0f;

    // seq lens packed (values <= 200 fit u8)
    u32 lenp = 0;
    #pragma unroll
    for (int r = 0; r < 4; ++r)
        lenp |= ((u32)slen[b0 + qr * 4 + r] & 255u) << (8 * r);

    // packed-entry index for col c = 16w + cl:  e = (w>>2)*64 + cl*4 + (w&3)
    const u32 eG = (u32)((w >> 2) * 64 + cl * 4 + (w & 3));
    const u32 cO = (u32)(16 * w + cl);            // output column
    u32 rowT[4];
    #pragma unroll
    for (int r = 0; r < 4; ++r)
        rowT[r] = (u32)(b0 + qr * 4 + r) * (u32)(T_ * 256);

    // wave-uniform weight bases (per-lane 16B fragments)
    const _Float16* pR = &g_Wh[((size_t)w * 4096) + lane * 8];          // R tile w
    const _Float16* pU = &g_Wh[((size_t)(16 + w) * 4096) + lane * 8];   // U tile 16+w
    const _Float16* pC = &wc_lds[w * 4096 + lane * 8];                  // C tile (LDS)

    float hold[4] = {};
    float uu[4];

    // ---- prologue: gate proj for t=0 ----
    u32 cg[4];
    #pragma unroll
    for (int r = 0; r < 4; ++r)
        cg[r] = pgI[rowT[r] + eG];

    for (int t = 0; t < T_; ++t) {
        const u32 tb = (u32)t * 256u;
        const u32 tn = (t + 1 < T_) ? tb + 256u : tb;  // last-step re-read discarded

        BARX();                                   // A: h(t-1) visible

        // ---- stream this step's R and U weight fragments (L2-hit) ----
        half8 fR[8], fU[8];
        #pragma unroll
        for (int s = 0; s < 8; ++s) fR[s] = *(const half8*)(pR + s * 512);
        #pragma unroll
        for (int s = 0; s < 8; ++s) fU[s] = *(const half8*)(pU + s * 512);

        // ---- gates: one ha read feeds both chains ----
        f32x4 aR = {}, aU = {};
        #pragma unroll
        for (int s = 0; s < 8; ++s) {
            half8 ha = *(const half8*)&h_lds[cl][s * 32 + qr * 8];
            aR = __builtin_amdgcn_mfma_f32_16x16x32_f16(ha, fR[s], aR, 0, 0, 0);
            aU = __builtin_amdgcn_mfma_f32_16x16x32_f16(ha, fU[s], aU, 0, 0, 0);
        }

        #pragma unroll
        for (int r = 0; r < 4; ++r) {
            float rv = sigmoid_f(aR[r] + f16f((u16)(cg[r] & 0xffffu)));
            uu[r]    = sigmoid_f(aU[r] + f16f((u16)(cg[r] >> 16)));
            rh_lds[qr * 4 + r][cO] = (_Float16)(rv * hold[r]);
        }

        // ---- reload gate proj for t+1; load cand proj for t (fly across B) ----
        #pragma unroll
        for (int r = 0; r < 4; ++r)
            cg[r] = pgI[rowT[r] + tn + eG];
        u16 ccr[4];
        #pragma unroll
        for (int r = 0; r < 4; ++r)
            ccr[r] = pcI[rowT[r] + tb + eG];

        BARX();                                   // B: rh visible

        // ---- candidate: Wc from LDS ----
        f32x4 aC = {};
        #pragma unroll
        for (int s = 0; s < 8; ++s) {
            half8 ra = *(const half8*)&rh_lds[cl][s * 32 + qr * 8];
            half8 wc = *(const half8*)(pC + s * 512);
            aC = __builtin_amdgcn_mfma_f32_16x16x32_f16(ra, wc, aC, 0, 0, 0);
        }

        // ---- finalize + stores ----
        #pragma unroll
        for (int r = 0; r < 4; ++r) {
            float cd = tanh_f(aC[r] + f16f(ccr[r]));
            float hn = uu[r] * hold[r] + (1.0f - uu[r]) * cd;
            bool valid = t < (int)((lenp >> (8 * r)) & 255u);
            out[rowT[r] + tb + cO] = valid ? hn : 0.0f;
            if (valid) {
                hold[r] = hn;
                h_lds[qr * 4 + r][cO] = (_Float16)hn;
            }
        }
    }
}

extern "C" void kernel_launch(void* const* d_in, const int* in_sizes, int n_in,
                              void* d_out, int out_size, void* d_ws, size_t ws_size,
                              hipStream_t stream) {
    const float* x    = (const float*)d_in[0];
    const int*   slen = (const int*)  d_in[1];
    const float* gk   = (const float*)d_in[2];
    const float* gb   = (const float*)d_in[3];
    const float* ck   = (const float*)d_in[4];
    const float* cb   = (const float*)d_in[5];
    float* out = (float*)d_out;
    u32*   pgI = (u32*)d_out;   // [102400][256] u32 == 104.86 MB == out size
    u16*   pcI = (u16*)d_ws;    // [102400][256] u16 == 52.4 MB

    prep_wt<<<dim3(96), 512, 0, stream>>>(gk, ck);
    proj_mfma<<<dim3(1600), 512, 0, stream>>>(x, gb, cb, pgI, pcI);
    gru_rec7<<<dim3(32), 1024, 0, stream>>>(slen, pgI, pcI, out);
}